// Round 6
// baseline (331.259 us; speedup 1.0000x reference)
//
#include <hip/hip_runtime.h>

// x: (64, 256, 56, 56) fp32.  Channel-block n:m sparsity:
//   mask1: keep top-2 of every 4 channels (ties kept, >= 2nd-largest |x|)
//   mask2: on residual (kept entries zeroed), keep top-1 of every 8 channels
//   out = x * (mask1 | mask2)
// Eliminated: L3-resident reads (R4), store cache mode (R5), DRAM run length
//   (R6), per-wave load pipelining (R7), copy-shaped access via LDS (R8).
//   Contradiction: reads demonstrably free + writes worth ~31 us at the
//   fill's 6.6 TB/s, yet kernel ~106-126 us. Counters show no busy pipe.
// R9 (this round): concurrency/residency probe. All prior versions ran ~20
//   waves/CU in thousands of short-lived lockstep-bursting blocks. The fill
//   (fastest memory kernel in this run) runs at 9.7% occupancy: few, long-
//   lived, steadily sweeping waves. In-flight arithmetic needs only ~11
//   KB/CU to saturate HBM; we had ~150 KB/CU of contending requests.
//   Now: 224 persistent blocks (1/CU via 100 KB LDS ballast), each walks 28
//   consecutive column-steps (114 KB contiguous per channel row), register
//   double-buffered so 8 nt loads stay in flight per wave. nt/nt.

#define N_IMG   64
#define C_CH    256
#define HW      3136            // 56*56
#define HW4     784             // float4s per channel row
#define CH_OCT  32              // C / 8
#define COLS    (N_IMG * HW4)   // 50176 float4-columns per channel row
#define CBLK    196             // column-blocks per octet (50176 / 256)
#define STEPS   6272            // CBLK * CH_OCT total column-steps
#define NBLK    224             // persistent blocks; 6272 / 224 = 28 steps each
#define SPB     28              // steps per block (consecutive -> same octet,
                                //   7 blocks cover one octet: 196/28 = 7)
#define BLK     256

typedef float vfloat4 __attribute__((ext_vector_type(4)));

__device__ __forceinline__ float second_largest4(float a, float b, float c, float d) {
    float mab = fmaxf(a, b), nab = fminf(a, b);
    float mcd = fmaxf(c, d), ncd = fminf(c, d);
    return fmaxf(fminf(mab, mcd), fmaxf(nab, ncd));
}

// In-place mask of 8 channels x 4 spatial.
__device__ __forceinline__ void mask_oct(vfloat4 v[8]) {
    #pragma unroll
    for (int e = 0; e < 4; ++e) {
        float a[8];
        #pragma unroll
        for (int c = 0; c < 8; ++c) a[c] = fabsf(v[c][e]);

        const float thr1a = second_largest4(a[0], a[1], a[2], a[3]);
        const float thr1b = second_largest4(a[4], a[5], a[6], a[7]);

        float res[8];
        bool  m1[8];
        #pragma unroll
        for (int c = 0; c < 4; ++c) { m1[c] = a[c] >= thr1a; res[c] = m1[c] ? 0.0f : a[c]; }
        #pragma unroll
        for (int c = 4; c < 8; ++c) { m1[c] = a[c] >= thr1b; res[c] = m1[c] ? 0.0f : a[c]; }

        float thr2 = res[0];
        #pragma unroll
        for (int c = 1; c < 8; ++c) thr2 = fmaxf(thr2, res[c]);

        #pragma unroll
        for (int c = 0; c < 8; ++c) {
            const bool keep = m1[c] | (res[c] >= thr2);
            v[c][e] = keep ? v[c][e] : 0.0f;
        }
    }
}

// Base (in float4 units) of column-step s for lane t: octet cb = s/CBLK,
// column col = (s%CBLK)*BLK + t, image n = col/HW4, spatial hw4 = col%HW4.
__device__ __forceinline__ size_t step_base(int s, int t) {
    const int cb   = s / CBLK;
    const int col  = (s - cb * CBLK) * BLK + t;
    const int n    = col / HW4;            // const divisor -> magic mul
    const int hw4  = col - n * HW4;
    return (size_t)n * (C_CH * HW4) + (size_t)cb * (8 * HW4) + (size_t)hw4;
}

__global__ __launch_bounds__(BLK) void sparsity_kernel(const float* __restrict__ x,
                                                       float* __restrict__ out) {
    // Occupancy ballast: 100 KB LDS forces exactly 1 block per CU (160 KB
    // pool). Guard is runtime-false but compiler-unprovable, so the
    // allocation isn't eliminated.
    __shared__ float ballast[25600];
    if ((size_t)x == 1) ballast[threadIdx.x] = 0.0f;

    const int t  = threadIdx.x;
    const int s0 = blockIdx.x * SPB;       // this block's first step

    const vfloat4* gx = (const vfloat4*)x;
    vfloat4*       go = (vfloat4*)out;

    vfloat4 cur[8], nxt[8];

    // Prologue: fill the pipe for step 0.
    {
        const size_t b = step_base(s0, t);
        #pragma unroll
        for (int c = 0; c < 8; ++c)
            cur[c] = __builtin_nontemporal_load(&gx[b + (size_t)c * HW4]);
    }

    size_t bcur = step_base(s0, t);
    for (int i = 0; i < SPB; ++i) {
        // Issue next step's loads first: keeps 8 nt loads in flight per wave
        // while this step's compute + stores run (__restrict__ -> legal).
        size_t bnxt = 0;
        if (i + 1 < SPB) {
            bnxt = step_base(s0 + i + 1, t);
            #pragma unroll
            for (int c = 0; c < 8; ++c)
                nxt[c] = __builtin_nontemporal_load(&gx[bnxt + (size_t)c * HW4]);
        }

        mask_oct(cur);

        #pragma unroll
        for (int c = 0; c < 8; ++c)
            __builtin_nontemporal_store(cur[c], &go[bcur + (size_t)c * HW4]);

        #pragma unroll
        for (int c = 0; c < 8; ++c) cur[c] = nxt[c];
        bcur = bnxt;
    }
}

extern "C" void kernel_launch(void* const* d_in, const int* in_sizes, int n_in,
                              void* d_out, int out_size, void* d_ws, size_t ws_size,
                              hipStream_t stream) {
    const float* x = (const float*)d_in[0];
    float* out = (float*)d_out;
    sparsity_kernel<<<dim3(NBLK), dim3(BLK), 0, stream>>>(x, out);
}